// Round 4
// baseline (485.723 us; speedup 1.0000x reference)
//
#include <hip/hip_runtime.h>
#include <math.h>

#define DIMC 512
#define HIDC 2048
#define EC   16
#define BC   8
#define NC   2048
#define CAPC 256
#define BN   (BC * NC)          // 16384 tokens
#define THRESH 0.8f

typedef unsigned short u16;
typedef __attribute__((ext_vector_type(8))) __bf16 bf16x8;
typedef __attribute__((ext_vector_type(4))) float f32x4;

__device__ __forceinline__ float bf2f(unsigned u) {
    union { unsigned i; float f; } v; v.i = u << 16; return v.f;
}
__device__ __forceinline__ u16 f2bf(float f) {
    union { float f; unsigned i; } v; v.f = f;
    unsigned r = v.i + 0x7fff + ((v.i >> 16) & 1);
    return (u16)(r >> 16);
}
// tanh-form gelu; |err| < 2e-4 for |x|<1.5 (hidden pre-act std ~0.29)
__device__ __forceinline__ float gelu_f(float x) {
    float u = 0.7978845608028654f * (x + 0.044715f * x * x * x);
    float t = __expf(2.f * u);
    float th = 1.f - 2.f / (t + 1.f);
    return 0.5f * x * (1.f + th);
}

// -------------------------------------------------- init (heads/pos_tok) ---
__global__ void init_kernel(int* __restrict__ heads, int* __restrict__ pos_tok)
{
    int i = blockIdx.x * 256 + threadIdx.x;
    if (i < EC * BC * CAPC) heads[i] = -1;
    if (i < BN) pos_tok[i] = 0;
}

// ------------------------------------------------------ fused gate kernel ---
__global__ __launch_bounds__(256) void gate_kernel(const float* __restrict__ x,
                                                   const float* __restrict__ wg,
                                                   float* __restrict__ raw,
                                                   float* __restrict__ weights,
                                                   float* __restrict__ maskf)
{
    __shared__ float wlds[16][516];
    __shared__ float lg[16][16];
    int t = threadIdx.x;
    int tok16 = t >> 4, e = t & 15;
    int token = blockIdx.x * 16 + tok16;

    {
        const float4* wg4 = (const float4*)wg;
#pragma unroll
        for (int j = 0; j < 8; ++j) {
            int idx4 = j * 256 + t;
            float4 v = wg4[idx4];
            int d  = idx4 >> 2;
            int e0 = (idx4 & 3) * 4;
            wlds[e0 + 0][d] = v.x;
            wlds[e0 + 1][d] = v.y;
            wlds[e0 + 2][d] = v.z;
            wlds[e0 + 3][d] = v.w;
        }
    }
    __syncthreads();

    const float4* xr = (const float4*)(x + (size_t)token * DIMC);
    const float4* wl = (const float4*)&wlds[e][0];
    float a0 = 0.f, a1 = 0.f, a2 = 0.f, a3 = 0.f;
#pragma unroll 4
    for (int i = 0; i < 128; i += 4) {
        float4 xa = xr[i], xb = xr[i+1], xc = xr[i+2], xd = xr[i+3];
        float4 wa = wl[i], wb = wl[i+1], wc = wl[i+2], wd = wl[i+3];
        a0 = fmaf(xa.w, wa.w, fmaf(xa.z, wa.z, fmaf(xa.y, wa.y, fmaf(xa.x, wa.x, a0))));
        a1 = fmaf(xb.w, wb.w, fmaf(xb.z, wb.z, fmaf(xb.y, wb.y, fmaf(xb.x, wb.x, a1))));
        a2 = fmaf(xc.w, wc.w, fmaf(xc.z, wc.z, fmaf(xc.y, wc.y, fmaf(xc.x, wc.x, a2))));
        a3 = fmaf(xd.w, wd.w, fmaf(xd.z, wd.z, fmaf(xd.y, wd.y, fmaf(xd.x, wd.x, a3))));
    }
    float logit = (a0 + a1) + (a2 + a3);

    float m = logit;
#pragma unroll
    for (int off = 8; off >= 1; off >>= 1) m = fmaxf(m, __shfl_xor(m, off, 16));
    float p = expf(logit - m);
    float s = p;
#pragma unroll
    for (int off = 8; off >= 1; off >>= 1) s += __shfl_xor(s, off, 16);
    p = p / s;

    int rank = 0;
    float cum = p;
#pragma unroll
    for (int j = 1; j < 16; ++j) {
        float op = __shfl_xor(p, j, 16);
        int oidx = e ^ j;
        bool ahead = (op > p) || (op == p && oidx < e);
        if (ahead) { rank++; cum += op; }
    }
    bool tm = (cum >= THRESH);
    int kr = tm ? rank : (EC - 1);
#pragma unroll
    for (int off = 8; off >= 1; off >>= 1) kr = min(kr, __shfl_xor(kr, off, 16));
    bool sel = (rank <= kr);

    float dsel = sel ? p : 0.f;
    float denom = dsel;
#pragma unroll
    for (int off = 8; off >= 1; off >>= 1) denom += __shfl_xor(denom, off, 16);
    float w = sel ? (p / denom) : 0.f;

    size_t o = (size_t)token * EC + e;
    raw[o]     = p;
    weights[o] = w;
    maskf[o]   = sel ? 1.f : 0.f;
    (void)lg;
}

// ------------------------------------------------------------- capacity ----
__global__ __launch_bounds__(64) void capacity_kernel(const float* __restrict__ raw,
                                                      float* __restrict__ maskf,
                                                      int* __restrict__ pos,
                                                      int* __restrict__ pos_tok,
                                                      float* __restrict__ density,
                                                      float* __restrict__ proxy)
{
    int t = blockIdx.x;
    int b = t / EC, e = t % EC;
    int lane = threadIdx.x;

    size_t idx = ((size_t)b * NC + lane) * EC + e;
    const size_t step = (size_t)64 * EC;
    float mv = maskf[idx];
    float rv = raw[idx];

    int count = 0;
    float rsum = 0.f;
    for (int n0 = 0; n0 < NC; n0 += 64) {
        float mn = 0.f, rn = 0.f;
        if (n0 + 64 < NC) { mn = maskf[idx + step]; rn = raw[idx + step]; }

        rsum += rv;
        unsigned long long bal = __ballot(mv != 0.f);
        int below = __popcll(bal & ((1ull << lane) - 1ull));
        int pval = 0;
        if (mv != 0.f) {
            pval = count + below;
            if (pval >= CAPC) { maskf[idx] = 0.f; pval = 0; }
            else if (pval > 0) atomicAdd(&pos_tok[b * NC + n0 + lane], pval);
        }
        pos[idx] = pval;
        count += __popcll(bal);

        idx += step; mv = mn; rv = rn;
    }
#pragma unroll
    for (int off = 32; off >= 1; off >>= 1) rsum += __shfl_xor(rsum, off);
    if (lane == 0) {
        int admitted = count < CAPC ? count : CAPC;
        density[t] = (float)admitted / (float)NC;
        proxy[t]   = rsum / (float)NC;
    }
}

// -------------------------------------------------- per-slot linked lists --
__global__ __launch_bounds__(256) void build_kernel(const float* __restrict__ maskf,
                                                    const int* __restrict__ pos,
                                                    const int* __restrict__ pos_tok,
                                                    int* __restrict__ heads,
                                                    int* __restrict__ nxt,
                                                    int* __restrict__ node_tok)
{
    int id = blockIdx.x * 256 + threadIdx.x;
    int token = id >> 4, e = id & 15;
    if (maskf[id] == 0.f) return;
    int c = pos_tok[token];
    if (c >= CAPC) return;
    int b = token >> 11;
    int slot = (e * BC + b) * CAPC + c;
    int node = (e * BC + b) * CAPC + pos[id];
    node_tok[node] = token;
    nxt[node] = atomicExch(&heads[slot], node);
}

// ------------------------------------------ gather -> expert inputs (bf16) --
__global__ __launch_bounds__(256) void gather_ei_kernel(const float* __restrict__ x,
                                                        const int* __restrict__ heads,
                                                        const int* __restrict__ nxt,
                                                        const int* __restrict__ node_tok,
                                                        u16* __restrict__ ei)
{
    int slot = blockIdx.x * 4 + (threadIdx.x >> 6);
    int lane = threadIdx.x & 63;
    float a[8] = {0,0,0,0,0,0,0,0};
    int node = heads[slot];
    while (node >= 0) {
        const float4* xr = (const float4*)(x + (size_t)node_tok[node] * DIMC) + lane * 2;
        float4 v0 = xr[0], v1 = xr[1];
        a[0]+=v0.x; a[1]+=v0.y; a[2]+=v0.z; a[3]+=v0.w;
        a[4]+=v1.x; a[5]+=v1.y; a[6]+=v1.z; a[7]+=v1.w;
        node = nxt[node];
    }
    uint4 v;
    v.x = (unsigned)f2bf(a[0]) | ((unsigned)f2bf(a[1]) << 16);
    v.y = (unsigned)f2bf(a[2]) | ((unsigned)f2bf(a[3]) << 16);
    v.z = (unsigned)f2bf(a[4]) | ((unsigned)f2bf(a[5]) << 16);
    v.w = (unsigned)f2bf(a[6]) | ((unsigned)f2bf(a[7]) << 16);
    *(uint4*)(ei + (size_t)slot * DIMC + lane * 8) = v;
}

// ------------- weight transpose + convert (w1 AND w2 in one dispatch) ------
__global__ __launch_bounds__(256) void transpose_cvt_all_kernel(const float* __restrict__ w1,
                                                                const float* __restrict__ w2,
                                                                u16* __restrict__ w1t,
                                                                u16* __restrict__ w2t)
{
    __shared__ float tile[64][65];
    int bid = blockIdx.x;
    const float* in; u16* out; int R, C, bx, by, e;
    if (bid < 4096) {
        e = bid >> 8; int r = bid & 255;
        bx = r & 31; by = r >> 5;
        in = w1; out = w1t; R = DIMC; C = HIDC;
    } else {
        bid -= 4096;
        e = bid >> 8; int r = bid & 255;
        bx = r & 7;  by = r >> 3;
        in = w2; out = w2t; R = HIDC; C = DIMC;
    }
    size_t eoff = (size_t)e * R * C;
    int c0 = bx * 64, r0 = by * 64;
    int tid = threadIdx.x;
    int rr = tid >> 4;
    int cc = (tid & 15) * 4;
#pragma unroll
    for (int i = 0; i < 4; ++i) {
        float4 v = *(const float4*)(in + eoff + (size_t)(r0 + rr + 16 * i) * C + c0 + cc);
        tile[rr + 16 * i][cc + 0] = v.x;
        tile[rr + 16 * i][cc + 1] = v.y;
        tile[rr + 16 * i][cc + 2] = v.z;
        tile[rr + 16 * i][cc + 3] = v.w;
    }
    __syncthreads();
    int c = tid >> 2;
    int r8 = (tid & 3) * 16;
    u16 buf[16];
#pragma unroll
    for (int j = 0; j < 16; ++j) buf[j] = f2bf(tile[r8 + j][c]);
    u16* op = out + eoff + (size_t)(c0 + c) * R + r0 + r8;
    *(uint4*)(op)     = *(uint4*)&buf[0];
    *(uint4*)(op + 8) = *(uint4*)&buf[8];
}

// --------------------------------------------------------- MFMA bf16 GEMM --
__device__ __forceinline__ void async_cp16(const u16* g, u16* l) {
    __builtin_amdgcn_global_load_lds(
        (const __attribute__((address_space(1))) unsigned*)g,
        (__attribute__((address_space(3))) unsigned*)l, 16, 0, 0);
}

#define GFENCE() asm volatile("" ::: "memory")
#define BAR() do { GFENCE(); __builtin_amdgcn_s_barrier(); GFENCE(); } while (0)

// ----- GEMM1: 256x256 tile, BK=64, 512 thr = 8 waves (2Mx4N), 4-phase -----
// (unchanged, passing since round 1)
template<int GELU>
__global__ __launch_bounds__(512, 2) void gemm256_kernel(
    const u16* __restrict__ A, const u16* __restrict__ Bt, u16* __restrict__ C,
    int M, int N, int K, long sA, long sB, long sC)
{
    __shared__ __align__(16) u16 lds[2][2][2][8192];
    const int e = blockIdx.z;
    const int bm = blockIdx.y * 256, bn = blockIdx.x * 256;
    const int t = threadIdx.x, lane = t & 63, w = t >> 6;
    const int wm = w & 1;
    const int wn = w >> 1;
    const int bh = wn >> 1;
    const int q = lane >> 4, m16 = lane & 15;

    const u16* g[2][2][2];
    int lofs[2];
#pragma unroll
    for (int j = 0; j < 2; ++j) {
        int l = j * 512 + t, r = l >> 3, c = (l & 7) ^ (r & 7);
        lofs[j] = l * 8;
        g[0][0][j] = A  + (size_t)e * sA + (size_t)(bm + r) * K + c * 8;
        g[0][1][j] = A  + (size_t)e * sA + (size_t)(bm + 128 + r) * K + c * 8;
        g[1][0][j] = Bt + (size_t)e * sB + (size_t)(bn + r) * K + c * 8;
        g[1][1][j] = Bt + (size_t)e * sB + (size_t)(bn + 128 + r) * K + c * 8;
    }

    int aro[8], bro[4];
#pragma unroll
    for (int mt = 0; mt < 8; ++mt) {
        int r = mt * 16 + m16;
        aro[mt] = r * 64 + (q ^ (r & 7)) * 8;
    }
#pragma unroll
    for (int nt = 0; nt < 4; ++nt) {
        int r = (wn & 1) * 64 + nt * 16 + m16;
        bro[nt] = r * 64 + (q ^ (r & 7)) * 8;
    }

    auto STAGE = [&](int buf, int op, int half) {
#pragma unroll
        for (int j = 0; j < 2; ++j) {
            async_cp16(g[op][half][j], &lds[buf][op][half][lofs[j]]);
            g[op][half][j] += 64;
        }
    };

    const int nk = K >> 6;
    STAGE(0, 1, 0); STAGE(0, 1, 1);
    STAGE(0, 0, 0); STAGE(0, 0, 1);
    if (nk > 1) {
        STAGE(1, 1, 0); STAGE(1, 1, 1);
        asm volatile("s_waitcnt vmcnt(4)" ::: "memory");
    } else {
        asm volatile("s_waitcnt vmcnt(0)" ::: "memory");
    }
    BAR();

    f32x4 acc[8][4] = {};
    for (int ti = 0; ti < nk; ++ti) {
        const int cur = ti & 1, nx = cur ^ 1;
        const u16* lA = &lds[cur][0][wm][0];
        const u16* lB = &lds[cur][1][bh][0];
        bf16x8 a0[4][2], a1[4][2], b01[2][2], b23[2][2];

        // ---- phase 1
#pragma unroll
        for (int mt = 0; mt < 4; ++mt)
#pragma unroll
            for (int kk = 0; kk < 2; ++kk)
                a0[mt][kk] = *(const bf16x8*)&lA[aro[mt] ^ (kk * 32)];
#pragma unroll
        for (int nt = 0; nt < 2; ++nt)
#pragma unroll
            for (int kk = 0; kk < 2; ++kk)
                b01[nt][kk] = *(const bf16x8*)&lB[bro[nt] ^ (kk * 32)];
        if (ti + 1 < nk) STAGE(nx, 0, 0);
        BAR();
        asm volatile("s_waitcnt lgkmcnt(0)" ::: "memory");
        __builtin_amdgcn_s_setprio(1);
#pragma unroll
        for (int mt = 0; mt < 4; ++mt)
#pragma unroll
            for (int nt = 0; nt < 2; ++nt)
#pragma unroll
                for (int kk = 0; kk < 2; ++kk)
                    acc[mt][nt] = __builtin_amdgcn_mfma_f32_16x16x32_bf16(
                        a0[mt][kk], b01[nt][kk], acc[mt][nt], 0, 0, 0);
        __builtin_amdgcn_s_setprio(0);
        BAR();

        // ---- phase 2
#pragma unroll
        for (int nt = 0; nt < 2; ++nt)
#pragma unroll
            for (int kk = 0; kk < 2; ++kk)
                b23[nt][kk] = *(const bf16x8*)&lB[bro[2 + nt] ^ (kk * 32)];
        if (ti + 1 < nk) STAGE(nx, 0, 1);
        BAR();
        asm volatile("s_waitcnt lgkmcnt(0)" ::: "memory");
        __builtin_amdgcn_s_setprio(1);
#pragma unroll
        for (int mt = 0; mt < 4; ++mt)
#pragma unroll
            for (int nt = 0; nt < 2; ++nt)
#pragma unroll
                for (int kk = 0; kk < 2; ++kk)
                    acc[mt][2 + nt] = __builtin_amdgcn_mfma_f32_16x16x32_bf16(
                        a0[mt][kk], b23[nt][kk], acc[mt][2 + nt], 0, 0, 0);
        __builtin_amdgcn_s_setprio(0);
        BAR();

        // ---- phase 3
#pragma unroll
        for (int mt = 0; mt < 4; ++mt)
#pragma unroll
            for (int kk = 0; kk < 2; ++kk)
                a1[mt][kk] = *(const bf16x8*)&lA[aro[4 + mt] ^ (kk * 32)];
        if (ti + 2 < nk) STAGE(cur, 1, 0);
        BAR();
        asm volatile("s_waitcnt lgkmcnt(0)" ::: "memory");
        __builtin_amdgcn_s_setprio(1);
#pragma unroll
        for (int mt = 0; mt < 4; ++mt)
#pragma unroll
            for (int nt = 0; nt < 2; ++nt)
#pragma unroll
                for (int kk = 0; kk < 2; ++kk)
                    acc[4 + mt][2 + nt] = __builtin_amdgcn_mfma_f32_16x16x32_bf16(
                        a1[mt][kk], b23[nt][kk], acc[4 + mt][2 + nt], 0, 0, 0);
        __builtin_amdgcn_s_setprio(0);
        BAR();

        // ---- phase 4
        if (ti + 2 < nk) STAGE(cur, 1, 1);
        BAR();
        __builtin_amdgcn_s_setprio(1);
#pragma unroll
        for (int mt = 0; mt < 4; ++mt)
#pragma unroll
            for (int nt = 0; nt < 2; ++nt)
#pragma unroll
                for (int kk = 0; kk < 2; ++kk)
                    acc[4 + mt][nt] = __builtin_amdgcn_mfma_f32_16x16x32_bf16(
                        a1[mt][kk], b01[nt][kk], acc[4 + mt][nt], 0, 0, 0);
        __builtin_amdgcn_s_setprio(0);
        if (ti + 1 < nk) {
            if (ti + 2 < nk) asm volatile("s_waitcnt vmcnt(4)" ::: "memory");
            else             asm volatile("s_waitcnt vmcnt(0)" ::: "memory");
        }
        BAR();
    }

    const size_t cbase = (size_t)e * sC;
#pragma unroll
    for (int mt = 0; mt < 8; ++mt)
#pragma unroll
        for (int nt = 0; nt < 4; ++nt)
#pragma unroll
            for (int r2 = 0; r2 < 4; ++r2) {
                int row = bm + wm * 128 + mt * 16 + q * 4 + r2;
                int col = bn + wn * 64 + nt * 16 + m16;
                float v = acc[mt][nt][r2];
                if (GELU) v = gelu_f(v);
                C[cbase + (size_t)row * N + col] = f2bf(v);
            }
}

// ----- GEMM2: 128x256 tile + fused scatter-combine epilogue ---------------
// Pipeline identical to round-3 (verified). Epilogue: instead of writing eo
// and running combine, each C row (= slot (e, b*CAPC+c)) walks the SAME
// linked list gather used (multi-token slots handled exactly like gather),
// and atomicAdd's weight-scaled f32 values straight into out[token][col].
// out is zeroed in-launch (graph-replay-safe hipMemsetAsync).
__global__ __launch_bounds__(512, 2) void gemm_ffn2_kernel(
    const u16* __restrict__ A, const u16* __restrict__ Bt,
    const int* __restrict__ heads, const int* __restrict__ nxt,
    const int* __restrict__ node_tok, const float* __restrict__ gatew,
    float* __restrict__ out,
    int e0, int N, int K, long sA, long sB)
{
    __shared__ __align__(16) u16 lds[2][3][8192];   // [buf][A|Bh0|Bh1] = 96 KiB
    const int e = blockIdx.z;
    const int bm = blockIdx.y * 128, bn = blockIdx.x * 256;
    const int t = threadIdx.x, lane = t & 63, w = t >> 6;
    const int wm = w & 1, wn = w >> 1;
    const int bh = wn >> 1;                          // wave's B half
    const int q = lane >> 4, m16 = lane & 15;

    const u16* gA[2]; const u16* gB[2][2];           // [half][chunk]
    int lofs[2];
#pragma unroll
    for (int j = 0; j < 2; ++j) {
        int l = j * 512 + t, r = l >> 3, c = (l & 7) ^ (r & 7);
        lofs[j] = l * 8;
        gA[j]    = A  + (size_t)e * sA + (size_t)(bm + r) * K + c * 8;
        gB[0][j] = Bt + (size_t)e * sB + (size_t)(bn + r) * K + c * 8;
        gB[1][j] = Bt + (size_t)e * sB + (size_t)(bn + 128 + r) * K + c * 8;
    }

    int aro[4], bro[4];
#pragma unroll
    for (int mt = 0; mt < 4; ++mt) {
        int r = wm * 64 + mt * 16 + m16;
        aro[mt] = r * 64 + (q ^ (r & 7)) * 8;
    }
#pragma unroll
    for (int nt = 0; nt < 4; ++nt) {
        int r = (wn & 1) * 64 + nt * 16 + m16;       // rows within the half
        bro[nt] = r * 64 + (q ^ (r & 7)) * 8;
    }

    auto STAGE_A = [&](int buf) {
#pragma unroll
        for (int j = 0; j < 2; ++j) { async_cp16(gA[j], &lds[buf][0][lofs[j]]); gA[j] += 64; }
    };
    auto STAGE_B = [&](int buf, int half) {
#pragma unroll
        for (int j = 0; j < 2; ++j) { async_cp16(gB[half][j], &lds[buf][1 + half][lofs[j]]); gB[half][j] += 64; }
    };

    const int nk = K >> 6;
    STAGE_A(0); STAGE_B(0, 0); STAGE_B(0, 1);
    if (nk > 1) {
        STAGE_B(1, 0); STAGE_B(1, 1);
        asm volatile("s_waitcnt vmcnt(4)" ::: "memory");   // tile0's 6 landed
    } else {
        asm volatile("s_waitcnt vmcnt(0)" ::: "memory");
    }
    BAR();

    f32x4 acc[4][4] = {};
    for (int ti = 0; ti < nk; ++ti) {
        const int cur = ti & 1, nx = cur ^ 1;
        const u16* lA = &lds[cur][0][0];
        const u16* lB = &lds[cur][1 + bh][0];
        bf16x8 a01[2][2], a23[2][2], b01[2][2], b23[2][2];

        // ---- phase 1: read a01 + b01 ; stage A(t+1)->nx ; Q(mt01,nt01)
#pragma unroll
        for (int mt = 0; mt < 2; ++mt)
#pragma unroll
            for (int kk = 0; kk < 2; ++kk)
                a01[mt][kk] = *(const bf16x8*)&lA[aro[mt] ^ (kk * 32)];
#pragma unroll
        for (int nt = 0; nt < 2; ++nt)
#pragma unroll
            for (int kk = 0; kk < 2; ++kk)
                b01[nt][kk] = *(const bf16x8*)&lB[bro[nt] ^ (kk * 32)];
        if (ti + 1 < nk) STAGE_A(nx);
        BAR();
        asm volatile("s_waitcnt lgkmcnt(0)" ::: "memory");
        __builtin_amdgcn_s_setprio(1);
#pragma unroll
        for (int mt = 0; mt < 2; ++mt)
#pragma unroll
            for (int nt = 0; nt < 2; ++nt)
#pragma unroll
                for (int kk = 0; kk < 2; ++kk)
                    acc[mt][nt] = __builtin_amdgcn_mfma_f32_16x16x32_bf16(
                        a01[mt][kk], b01[nt][kk], acc[mt][nt], 0, 0, 0);
        __builtin_amdgcn_s_setprio(0);
        BAR();

        // ---- phase 2: read b23 ; Q(mt01,nt23)
#pragma unroll
        for (int nt = 0; nt < 2; ++nt)
#pragma unroll
            for (int kk = 0; kk < 2; ++kk)
                b23[nt][kk] = *(const bf16x8*)&lB[bro[2 + nt] ^ (kk * 32)];
        BAR();
        asm volatile("s_waitcnt lgkmcnt(0)" ::: "memory");
        __builtin_amdgcn_s_setprio(1);
#pragma unroll
        for (int mt = 0; mt < 2; ++mt)
#pragma unroll
            for (int nt = 0; nt < 2; ++nt)
#pragma unroll
                for (int kk = 0; kk < 2; ++kk)
                    acc[mt][2 + nt] = __builtin_amdgcn_mfma_f32_16x16x32_bf16(
                        a01[mt][kk], b23[nt][kk], acc[mt][2 + nt], 0, 0, 0);
        __builtin_amdgcn_s_setprio(0);
        BAR();

        // ---- phase 3: read a23 ; stage B(t+2)h0->cur ; Q(mt23,nt23)
#pragma unroll
        for (int mt = 0; mt < 2; ++mt)
#pragma unroll
            for (int kk = 0; kk < 2; ++kk)
                a23[mt][kk] = *(const bf16x8*)&lA[aro[2 + mt] ^ (kk * 32)];
        if (ti + 2 < nk) STAGE_B(cur, 0);
        BAR();
        asm volatile("s_waitcnt lgkmcnt(0)" ::: "memory");
        __builtin_amdgcn_s_setprio(1);
#pragma unroll
        for (int mt = 0; mt < 2; ++mt)
#pragma unroll
            for (int nt = 0; nt < 2; ++nt)
#pragma unroll
                for (int kk = 0; kk < 2; ++kk)
                    acc[2 + mt][2 + nt] = __builtin_amdgcn_mfma_f32_16x16x32_bf16(
                        a23[mt][kk], b23[nt][kk], acc[2 + mt][2 + nt], 0, 0, 0);
        __builtin_amdgcn_s_setprio(0);
        BAR();

        // ---- phase 4: stage B(t+2)h1->cur ; Q(mt23,nt01) ; counted vmcnt
        if (ti + 2 < nk) STAGE_B(cur, 1);
        BAR();
        __builtin_amdgcn_s_setprio(1);
#pragma unroll
        for (int mt = 0; mt < 2; ++mt)
#pragma unroll
            for (int nt = 0; nt < 2; ++nt)
#pragma unroll
                for (int kk = 0; kk < 2; ++kk)
                    acc[2 + mt][nt] = __builtin_amdgcn_mfma_f32_16x16x32_bf16(
                        a23[mt][kk], b01[nt][kk], acc[2 + mt][nt], 0, 0, 0);
        __builtin_amdgcn_s_setprio(0);
        if (ti + 1 < nk) {
            if (ti + 2 < nk) asm volatile("s_waitcnt vmcnt(4)" ::: "memory");
            else             asm volatile("s_waitcnt vmcnt(0)" ::: "memory");
        }
        BAR();
    }

    // ---- scatter-combine epilogue ----
    // C-row (within expert) = bm + wm*64 + mt*16 + q*4 + r2 = b*CAPC + c.
    // slot = (e0+e)*BC*CAPC + row. Walk the list; each node is an admitted
    // (token, expert) pair -> out[token][col] += w(token,e) * acc.
    const int eg = e0 + e;
    const int sbase = eg * BC * CAPC;
    // prefetch heads for my 16 rows (independent loads)
    int hd[16];
#pragma unroll
    for (int mt = 0; mt < 4; ++mt)
#pragma unroll
        for (int r2 = 0; r2 < 4; ++r2) {
            int row = bm + wm * 64 + mt * 16 + q * 4 + r2;
            hd[mt * 4 + r2] = heads[sbase + row];
        }
#pragma unroll
    for (int mt = 0; mt < 4; ++mt)
#pragma unroll
        for (int r2 = 0; r2 < 4; ++r2) {
            int node = hd[mt * 4 + r2];
            while (node >= 0) {
                int token = node_tok[node];
                int nx2 = nxt[node];
                float wv = gatew[(size_t)token * EC + eg];
                float* orow = out + (size_t)token * DIMC;
#pragma unroll
                for (int nt = 0; nt < 4; ++nt) {
                    int col = bn + wn * 64 + nt * 16 + m16;
                    atomicAdd(&orow[col], wv * acc[mt][nt][r2]);
                }
                node = nx2;
            }
        }
}

__global__ void loss_kernel(const float* __restrict__ density,
                            const float* __restrict__ proxy,
                            float* __restrict__ out_loss)
{
    __shared__ float sh[BC * EC];
    int t = threadIdx.x;
    sh[t] = density[t] * proxy[t];
    __syncthreads();
    for (int s2 = (BC * EC) / 2; s2 >= 1; s2 >>= 1) {
        if (t < s2) sh[t] += sh[t + s2];
        __syncthreads();
    }
    if (t == 0)
        out_loss[0] = sh[0] * ((float)(EC * EC) / (float)(BC * EC)) * 0.01f;
}

// ---------------------------------------------------------------- launch ---
extern "C" void kernel_launch(void* const* d_in, const int* in_sizes, int n_in,
                              void* d_out, int out_size, void* d_ws, size_t ws_size,
                              hipStream_t stream)
{
    const float* x  = (const float*)d_in[0];
    const float* wg = (const float*)d_in[1];
    const float* w1 = (const float*)d_in[2];
    const float* w2 = (const float*)d_in[3];
    float* out = (float*)d_out;

    char* ws = (char*)d_ws;
    size_t off = 0;
    auto alloc = [&](size_t bytes) -> void* {
        void* p = ws + off;
        off = (off + bytes + 255) & ~(size_t)255;
        return p;
    };
    float* raw      = (float*)alloc((size_t)BN * EC * 4);
    float* weights  = (float*)alloc((size_t)BN * EC * 4);
    float* maskf    = (float*)alloc((size_t)BN * EC * 4);
    int*   pos      = (int*)  alloc((size_t)BN * EC * 4);
    int*   pos_tok  = (int*)  alloc((size_t)BN * 4);
    int*   heads    = (int*)  alloc((size_t)EC * BC * CAPC * 4);
    int*   nxt      = (int*)  alloc((size_t)EC * BC * CAPC * 4);
    int*   node_tok = (int*)  alloc((size_t)EC * BC * CAPC * 4);
    float* density  = (float*)alloc(BC * EC * 4);
    float* proxy    = (float*)alloc(BC * EC * 4);
    u16*   ei_bf    = (u16*)alloc((size_t)EC * BC * CAPC * DIMC * 2);
    u16*   w1t      = (u16*)alloc((size_t)EC * DIMC * HIDC * 2);
    u16*   w2t      = (u16*)alloc((size_t)EC * HIDC * DIMC * 2);
    size_t hid_full = (size_t)EC * BC * CAPC * HIDC * 2;     // 128 MiB
    int ngroups = (ws_size - off >= hid_full) ? 1 : 2;
    int EG = EC / ngroups;
    u16* hidden = (u16*)alloc((size_t)EG * BC * CAPC * HIDC * 2);

    (void)in_sizes; (void)n_in; (void)out_size;

    hipMemsetAsync(out, 0, (size_t)BN * DIMC * 4, stream);
    init_kernel<<<(EC * BC * CAPC + 255) / 256, 256, 0, stream>>>(heads, pos_tok);
    transpose_cvt_all_kernel<<<8192, 256, 0, stream>>>(w1, w2, w1t, w2t);

    gate_kernel<<<BN / 16, 256, 0, stream>>>(x, wg, raw, weights, maskf);
    capacity_kernel<<<BC * EC, 64, 0, stream>>>(raw, maskf, pos, pos_tok, density, proxy);
    build_kernel<<<BN * EC / 256, 256, 0, stream>>>(maskf, pos, pos_tok, heads, nxt, node_tok);
    gather_ei_kernel<<<EC * BC * CAPC / 4, 256, 0, stream>>>(x, heads, nxt, node_tok, ei_bf);

    for (int g = 0; g < ngroups; ++g) {
        const u16* Ag  = ei_bf + (size_t)g * EG * BC * CAPC * DIMC;
        const u16* B1g = w1t   + (size_t)g * EG * DIMC * HIDC;
        gemm256_kernel<1><<<dim3(HIDC / 256, (BC * CAPC) / 256, EG), 512, 0, stream>>>(
            Ag, B1g, hidden, BC * CAPC, HIDC, DIMC,
            (long)BC * CAPC * DIMC, (long)HIDC * DIMC, (long)BC * CAPC * HIDC);
        const u16* B2g = w2t + (size_t)g * EG * HIDC * DIMC;
        gemm_ffn2_kernel<<<dim3(DIMC / 256, (BC * CAPC) / 128, EG), 512, 0, stream>>>(
            hidden, B2g, heads, nxt, node_tok, weights, out,
            g * EG, DIMC, HIDC,
            (long)BC * CAPC * HIDC, (long)DIMC * HIDC);
    }

    loss_kernel<<<1, BC * EC, 0, stream>>>(density, proxy, out + (size_t)BN * DIMC);
}

// Round 5
// 445.540 us; speedup vs baseline: 1.0902x; 1.0902x over previous
//
#include <hip/hip_runtime.h>
#include <math.h>

#define DIMC 512
#define HIDC 2048
#define EC   16
#define BC   8
#define NC   2048
#define CAPC 256
#define BN   (BC * NC)          // 16384 tokens
#define THRESH 0.8f

typedef unsigned short u16;
typedef __attribute__((ext_vector_type(8))) __bf16 bf16x8;
typedef __attribute__((ext_vector_type(4))) float f32x4;

__device__ __forceinline__ float bf2f(unsigned u) {
    union { unsigned i; float f; } v; v.i = u << 16; return v.f;
}
__device__ __forceinline__ u16 f2bf(float f) {
    union { float f; unsigned i; } v; v.f = f;
    unsigned r = v.i + 0x7fff + ((v.i >> 16) & 1);
    return (u16)(r >> 16);
}
// tanh-form gelu; |err| < 2e-4 for |x|<1.5 (hidden pre-act std ~0.29)
__device__ __forceinline__ float gelu_f(float x) {
    float u = 0.7978845608028654f * (x + 0.044715f * x * x * x);
    float t = __expf(2.f * u);
    float th = 1.f - 2.f / (t + 1.f);
    return 0.5f * x * (1.f + th);
}

// -------------------------------------------------- init (heads/pos_tok) ---
__global__ void init_kernel(int* __restrict__ heads, int* __restrict__ pos_tok)
{
    int i = blockIdx.x * 256 + threadIdx.x;
    if (i < EC * BC * CAPC) heads[i] = -1;
    if (i < BN) pos_tok[i] = 0;
}

// ------------------------------------------------------ fused gate kernel ---
__global__ __launch_bounds__(256) void gate_kernel(const float* __restrict__ x,
                                                   const float* __restrict__ wg,
                                                   float* __restrict__ raw,
                                                   float* __restrict__ weights,
                                                   float* __restrict__ maskf)
{
    __shared__ float wlds[16][516];
    __shared__ float lg[16][16];
    int t = threadIdx.x;
    int tok16 = t >> 4, e = t & 15;
    int token = blockIdx.x * 16 + tok16;

    {
        const float4* wg4 = (const float4*)wg;
#pragma unroll
        for (int j = 0; j < 8; ++j) {
            int idx4 = j * 256 + t;
            float4 v = wg4[idx4];
            int d  = idx4 >> 2;
            int e0 = (idx4 & 3) * 4;
            wlds[e0 + 0][d] = v.x;
            wlds[e0 + 1][d] = v.y;
            wlds[e0 + 2][d] = v.z;
            wlds[e0 + 3][d] = v.w;
        }
    }
    __syncthreads();

    const float4* xr = (const float4*)(x + (size_t)token * DIMC);
    const float4* wl = (const float4*)&wlds[e][0];
    float a0 = 0.f, a1 = 0.f, a2 = 0.f, a3 = 0.f;
#pragma unroll 4
    for (int i = 0; i < 128; i += 4) {
        float4 xa = xr[i], xb = xr[i+1], xc = xr[i+2], xd = xr[i+3];
        float4 wa = wl[i], wb = wl[i+1], wc = wl[i+2], wd = wl[i+3];
        a0 = fmaf(xa.w, wa.w, fmaf(xa.z, wa.z, fmaf(xa.y, wa.y, fmaf(xa.x, wa.x, a0))));
        a1 = fmaf(xb.w, wb.w, fmaf(xb.z, wb.z, fmaf(xb.y, wb.y, fmaf(xb.x, wb.x, a1))));
        a2 = fmaf(xc.w, wc.w, fmaf(xc.z, wc.z, fmaf(xc.y, wc.y, fmaf(xc.x, wc.x, a2))));
        a3 = fmaf(xd.w, wd.w, fmaf(xd.z, wd.z, fmaf(xd.y, wd.y, fmaf(xd.x, wd.x, a3))));
    }
    float logit = (a0 + a1) + (a2 + a3);

    float m = logit;
#pragma unroll
    for (int off = 8; off >= 1; off >>= 1) m = fmaxf(m, __shfl_xor(m, off, 16));
    float p = expf(logit - m);
    float s = p;
#pragma unroll
    for (int off = 8; off >= 1; off >>= 1) s += __shfl_xor(s, off, 16);
    p = p / s;

    int rank = 0;
    float cum = p;
#pragma unroll
    for (int j = 1; j < 16; ++j) {
        float op = __shfl_xor(p, j, 16);
        int oidx = e ^ j;
        bool ahead = (op > p) || (op == p && oidx < e);
        if (ahead) { rank++; cum += op; }
    }
    bool tm = (cum >= THRESH);
    int kr = tm ? rank : (EC - 1);
#pragma unroll
    for (int off = 8; off >= 1; off >>= 1) kr = min(kr, __shfl_xor(kr, off, 16));
    bool sel = (rank <= kr);

    float dsel = sel ? p : 0.f;
    float denom = dsel;
#pragma unroll
    for (int off = 8; off >= 1; off >>= 1) denom += __shfl_xor(denom, off, 16);
    float w = sel ? (p / denom) : 0.f;

    size_t o = (size_t)token * EC + e;
    raw[o]     = p;
    weights[o] = w;
    maskf[o]   = sel ? 1.f : 0.f;
    (void)lg;
}

// ------------------------------------------------------------- capacity ----
__global__ __launch_bounds__(64) void capacity_kernel(const float* __restrict__ raw,
                                                      float* __restrict__ maskf,
                                                      int* __restrict__ pos,
                                                      int* __restrict__ pos_tok,
                                                      float* __restrict__ density,
                                                      float* __restrict__ proxy)
{
    int t = blockIdx.x;
    int b = t / EC, e = t % EC;
    int lane = threadIdx.x;

    size_t idx = ((size_t)b * NC + lane) * EC + e;
    const size_t step = (size_t)64 * EC;
    float mv = maskf[idx];
    float rv = raw[idx];

    int count = 0;
    float rsum = 0.f;
    for (int n0 = 0; n0 < NC; n0 += 64) {
        float mn = 0.f, rn = 0.f;
        if (n0 + 64 < NC) { mn = maskf[idx + step]; rn = raw[idx + step]; }

        rsum += rv;
        unsigned long long bal = __ballot(mv != 0.f);
        int below = __popcll(bal & ((1ull << lane) - 1ull));
        int pval = 0;
        if (mv != 0.f) {
            pval = count + below;
            if (pval >= CAPC) { maskf[idx] = 0.f; pval = 0; }
            else if (pval > 0) atomicAdd(&pos_tok[b * NC + n0 + lane], pval);
        }
        pos[idx] = pval;
        count += __popcll(bal);

        idx += step; mv = mn; rv = rn;
    }
#pragma unroll
    for (int off = 32; off >= 1; off >>= 1) rsum += __shfl_xor(rsum, off);
    if (lane == 0) {
        int admitted = count < CAPC ? count : CAPC;
        density[t] = (float)admitted / (float)NC;
        proxy[t]   = rsum / (float)NC;
    }
}

// -------------------------------------------------- per-slot linked lists --
__global__ __launch_bounds__(256) void build_kernel(const float* __restrict__ maskf,
                                                    const int* __restrict__ pos,
                                                    const int* __restrict__ pos_tok,
                                                    int* __restrict__ heads,
                                                    int* __restrict__ nxt,
                                                    int* __restrict__ node_tok)
{
    int id = blockIdx.x * 256 + threadIdx.x;
    int token = id >> 4, e = id & 15;
    if (maskf[id] == 0.f) return;
    int c = pos_tok[token];
    if (c >= CAPC) return;
    int b = token >> 11;
    int slot = (e * BC + b) * CAPC + c;
    int node = (e * BC + b) * CAPC + pos[id];
    node_tok[node] = token;
    nxt[node] = atomicExch(&heads[slot], node);
}

// ------------------------------------------ gather -> expert inputs (bf16) --
__global__ __launch_bounds__(256) void gather_ei_kernel(const float* __restrict__ x,
                                                        const int* __restrict__ heads,
                                                        const int* __restrict__ nxt,
                                                        const int* __restrict__ node_tok,
                                                        u16* __restrict__ ei)
{
    int slot = blockIdx.x * 4 + (threadIdx.x >> 6);
    int lane = threadIdx.x & 63;
    float a[8] = {0,0,0,0,0,0,0,0};
    int node = heads[slot];
    while (node >= 0) {
        const float4* xr = (const float4*)(x + (size_t)node_tok[node] * DIMC) + lane * 2;
        float4 v0 = xr[0], v1 = xr[1];
        a[0]+=v0.x; a[1]+=v0.y; a[2]+=v0.z; a[3]+=v0.w;
        a[4]+=v1.x; a[5]+=v1.y; a[6]+=v1.z; a[7]+=v1.w;
        node = nxt[node];
    }
    uint4 v;
    v.x = (unsigned)f2bf(a[0]) | ((unsigned)f2bf(a[1]) << 16);
    v.y = (unsigned)f2bf(a[2]) | ((unsigned)f2bf(a[3]) << 16);
    v.z = (unsigned)f2bf(a[4]) | ((unsigned)f2bf(a[5]) << 16);
    v.w = (unsigned)f2bf(a[6]) | ((unsigned)f2bf(a[7]) << 16);
    *(uint4*)(ei + (size_t)slot * DIMC + lane * 8) = v;
}

// ------------- weight transpose + convert (w1 AND w2 in one dispatch) ------
__global__ __launch_bounds__(256) void transpose_cvt_all_kernel(const float* __restrict__ w1,
                                                                const float* __restrict__ w2,
                                                                u16* __restrict__ w1t,
                                                                u16* __restrict__ w2t)
{
    __shared__ float tile[64][65];
    int bid = blockIdx.x;
    const float* in; u16* out; int R, C, bx, by, e;
    if (bid < 4096) {
        e = bid >> 8; int r = bid & 255;
        bx = r & 31; by = r >> 5;
        in = w1; out = w1t; R = DIMC; C = HIDC;
    } else {
        bid -= 4096;
        e = bid >> 8; int r = bid & 255;
        bx = r & 7;  by = r >> 3;
        in = w2; out = w2t; R = HIDC; C = DIMC;
    }
    size_t eoff = (size_t)e * R * C;
    int c0 = bx * 64, r0 = by * 64;
    int tid = threadIdx.x;
    int rr = tid >> 4;
    int cc = (tid & 15) * 4;
#pragma unroll
    for (int i = 0; i < 4; ++i) {
        float4 v = *(const float4*)(in + eoff + (size_t)(r0 + rr + 16 * i) * C + c0 + cc);
        tile[rr + 16 * i][cc + 0] = v.x;
        tile[rr + 16 * i][cc + 1] = v.y;
        tile[rr + 16 * i][cc + 2] = v.z;
        tile[rr + 16 * i][cc + 3] = v.w;
    }
    __syncthreads();
    int c = tid >> 2;
    int r8 = (tid & 3) * 16;
    u16 buf[16];
#pragma unroll
    for (int j = 0; j < 16; ++j) buf[j] = f2bf(tile[r8 + j][c]);
    u16* op = out + eoff + (size_t)(c0 + c) * R + r0 + r8;
    *(uint4*)(op)     = *(uint4*)&buf[0];
    *(uint4*)(op + 8) = *(uint4*)&buf[8];
}

// --------------------------------------------------------- MFMA bf16 GEMM --
__device__ __forceinline__ void async_cp16(const u16* g, u16* l) {
    __builtin_amdgcn_global_load_lds(
        (const __attribute__((address_space(1))) unsigned*)g,
        (__attribute__((address_space(3))) unsigned*)l, 16, 0, 0);
}

#define GFENCE() asm volatile("" ::: "memory")
#define BAR() do { GFENCE(); __builtin_amdgcn_s_barrier(); GFENCE(); } while (0)

// Chunked XCD swizzle (bijective when gridDim.x % 8 == 0): XCD k gets a
// CONTIGUOUS chunk of the decomposed id space -> with EG=8 each XCD owns
// exactly one expert (GEMM1: 4MB A+B working set = its private L2).
__device__ __forceinline__ int xcd_swz(int id, int nwg) {
    int chunk = nwg >> 3;
    return (id & 7) * chunk + (id >> 3);
}

// ----- GEMM1: 256x256 tile, BK=64, 512 thr = 8 waves (2Mx4N), 4-phase -----
// 1D grid, internally decomposed with XCD swizzle. Pipeline unchanged.
template<int GELU>
__global__ __launch_bounds__(512, 2) void gemm256_kernel(
    const u16* __restrict__ A, const u16* __restrict__ Bt, u16* __restrict__ C,
    int M, int N, int K, long sA, long sB, long sC)
{
    __shared__ __align__(16) u16 lds[2][2][2][8192];
    const int bxc = N >> 8, byc = M >> 8;
    int swzid = xcd_swz(blockIdx.x, gridDim.x);
    const int e  = swzid / (bxc * byc);
    int rr2 = swzid % (bxc * byc);
    const int bm = (rr2 / bxc) * 256, bn = (rr2 % bxc) * 256;
    const int t = threadIdx.x, lane = t & 63, w = t >> 6;
    const int wm = w & 1;
    const int wn = w >> 1;
    const int bh = wn >> 1;
    const int q = lane >> 4, m16 = lane & 15;

    const u16* g[2][2][2];
    int lofs[2];
#pragma unroll
    for (int j = 0; j < 2; ++j) {
        int l = j * 512 + t, r = l >> 3, c = (l & 7) ^ (r & 7);
        lofs[j] = l * 8;
        g[0][0][j] = A  + (size_t)e * sA + (size_t)(bm + r) * K + c * 8;
        g[0][1][j] = A  + (size_t)e * sA + (size_t)(bm + 128 + r) * K + c * 8;
        g[1][0][j] = Bt + (size_t)e * sB + (size_t)(bn + r) * K + c * 8;
        g[1][1][j] = Bt + (size_t)e * sB + (size_t)(bn + 128 + r) * K + c * 8;
    }

    int aro[8], bro[4];
#pragma unroll
    for (int mt = 0; mt < 8; ++mt) {
        int r = mt * 16 + m16;
        aro[mt] = r * 64 + (q ^ (r & 7)) * 8;
    }
#pragma unroll
    for (int nt = 0; nt < 4; ++nt) {
        int r = (wn & 1) * 64 + nt * 16 + m16;
        bro[nt] = r * 64 + (q ^ (r & 7)) * 8;
    }

    auto STAGE = [&](int buf, int op, int half) {
#pragma unroll
        for (int j = 0; j < 2; ++j) {
            async_cp16(g[op][half][j], &lds[buf][op][half][lofs[j]]);
            g[op][half][j] += 64;
        }
    };

    const int nk = K >> 6;
    STAGE(0, 1, 0); STAGE(0, 1, 1);
    STAGE(0, 0, 0); STAGE(0, 0, 1);
    if (nk > 1) {
        STAGE(1, 1, 0); STAGE(1, 1, 1);
        asm volatile("s_waitcnt vmcnt(4)" ::: "memory");
    } else {
        asm volatile("s_waitcnt vmcnt(0)" ::: "memory");
    }
    BAR();

    f32x4 acc[8][4] = {};
    for (int ti = 0; ti < nk; ++ti) {
        const int cur = ti & 1, nx = cur ^ 1;
        const u16* lA = &lds[cur][0][wm][0];
        const u16* lB = &lds[cur][1][bh][0];
        bf16x8 a0[4][2], a1[4][2], b01[2][2], b23[2][2];

        // ---- phase 1
#pragma unroll
        for (int mt = 0; mt < 4; ++mt)
#pragma unroll
            for (int kk = 0; kk < 2; ++kk)
                a0[mt][kk] = *(const bf16x8*)&lA[aro[mt] ^ (kk * 32)];
#pragma unroll
        for (int nt = 0; nt < 2; ++nt)
#pragma unroll
            for (int kk = 0; kk < 2; ++kk)
                b01[nt][kk] = *(const bf16x8*)&lB[bro[nt] ^ (kk * 32)];
        if (ti + 1 < nk) STAGE(nx, 0, 0);
        BAR();
        asm volatile("s_waitcnt lgkmcnt(0)" ::: "memory");
        __builtin_amdgcn_s_setprio(1);
#pragma unroll
        for (int mt = 0; mt < 4; ++mt)
#pragma unroll
            for (int nt = 0; nt < 2; ++nt)
#pragma unroll
                for (int kk = 0; kk < 2; ++kk)
                    acc[mt][nt] = __builtin_amdgcn_mfma_f32_16x16x32_bf16(
                        a0[mt][kk], b01[nt][kk], acc[mt][nt], 0, 0, 0);
        __builtin_amdgcn_s_setprio(0);
        BAR();

        // ---- phase 2
#pragma unroll
        for (int nt = 0; nt < 2; ++nt)
#pragma unroll
            for (int kk = 0; kk < 2; ++kk)
                b23[nt][kk] = *(const bf16x8*)&lB[bro[2 + nt] ^ (kk * 32)];
        if (ti + 1 < nk) STAGE(nx, 0, 1);
        BAR();
        asm volatile("s_waitcnt lgkmcnt(0)" ::: "memory");
        __builtin_amdgcn_s_setprio(1);
#pragma unroll
        for (int mt = 0; mt < 4; ++mt)
#pragma unroll
            for (int nt = 0; nt < 2; ++nt)
#pragma unroll
                for (int kk = 0; kk < 2; ++kk)
                    acc[mt][2 + nt] = __builtin_amdgcn_mfma_f32_16x16x32_bf16(
                        a0[mt][kk], b23[nt][kk], acc[mt][2 + nt], 0, 0, 0);
        __builtin_amdgcn_s_setprio(0);
        BAR();

        // ---- phase 3
#pragma unroll
        for (int mt = 0; mt < 4; ++mt)
#pragma unroll
            for (int kk = 0; kk < 2; ++kk)
                a1[mt][kk] = *(const bf16x8*)&lA[aro[4 + mt] ^ (kk * 32)];
        if (ti + 2 < nk) STAGE(cur, 1, 0);
        BAR();
        asm volatile("s_waitcnt lgkmcnt(0)" ::: "memory");
        __builtin_amdgcn_s_setprio(1);
#pragma unroll
        for (int mt = 0; mt < 4; ++mt)
#pragma unroll
            for (int nt = 0; nt < 2; ++nt)
#pragma unroll
                for (int kk = 0; kk < 2; ++kk)
                    acc[4 + mt][2 + nt] = __builtin_amdgcn_mfma_f32_16x16x32_bf16(
                        a1[mt][kk], b23[nt][kk], acc[4 + mt][2 + nt], 0, 0, 0);
        __builtin_amdgcn_s_setprio(0);
        BAR();

        // ---- phase 4
        if (ti + 2 < nk) STAGE(cur, 1, 1);
        BAR();
        __builtin_amdgcn_s_setprio(1);
#pragma unroll
        for (int mt = 0; mt < 4; ++mt)
#pragma unroll
            for (int nt = 0; nt < 2; ++nt)
#pragma unroll
                for (int kk = 0; kk < 2; ++kk)
                    acc[4 + mt][nt] = __builtin_amdgcn_mfma_f32_16x16x32_bf16(
                        a1[mt][kk], b01[nt][kk], acc[4 + mt][nt], 0, 0, 0);
        __builtin_amdgcn_s_setprio(0);
        if (ti + 1 < nk) {
            if (ti + 2 < nk) asm volatile("s_waitcnt vmcnt(4)" ::: "memory");
            else             asm volatile("s_waitcnt vmcnt(0)" ::: "memory");
        }
        BAR();
    }

    const size_t cbase = (size_t)e * sC;
#pragma unroll
    for (int mt = 0; mt < 8; ++mt)
#pragma unroll
        for (int nt = 0; nt < 4; ++nt)
#pragma unroll
            for (int r2 = 0; r2 < 4; ++r2) {
                int row = bm + wm * 128 + mt * 16 + q * 4 + r2;
                int col = bn + wn * 64 + nt * 16 + m16;
                float v = acc[mt][nt][r2];
                if (GELU) v = gelu_f(v);
                C[cbase + (size_t)row * N + col] = f2bf(v);
            }
}

// ----- GEMM2: 128x256 tile, BK=64, 512 thr = 8 waves (2Mx4N, 64x64/wave) ---
// 1D grid + XCD swizzle; pipeline = verified round-3 schedule.
__global__ __launch_bounds__(512, 2) void gemm_ffn2_kernel(
    const u16* __restrict__ A, const u16* __restrict__ Bt, u16* __restrict__ C,
    int N, int K, long sA, long sB, long sC)
{
    __shared__ __align__(16) u16 lds[2][3][8192];   // [buf][A|Bh0|Bh1] = 96 KiB
    const int bxc = N >> 8, byc = 2048 >> 7;        // M = BC*CAPC = 2048
    int swzid = xcd_swz(blockIdx.x, gridDim.x);
    const int e  = swzid / (bxc * byc);
    int rr2 = swzid % (bxc * byc);
    const int bm = (rr2 / bxc) * 128, bn = (rr2 % bxc) * 256;
    const int t = threadIdx.x, lane = t & 63, w = t >> 6;
    const int wm = w & 1, wn = w >> 1;
    const int bh = wn >> 1;                          // wave's B half
    const int q = lane >> 4, m16 = lane & 15;

    const u16* gA[2]; const u16* gB[2][2];           // [half][chunk]
    int lofs[2];
#pragma unroll
    for (int j = 0; j < 2; ++j) {
        int l = j * 512 + t, r = l >> 3, c = (l & 7) ^ (r & 7);
        lofs[j] = l * 8;
        gA[j]    = A  + (size_t)e * sA + (size_t)(bm + r) * K + c * 8;
        gB[0][j] = Bt + (size_t)e * sB + (size_t)(bn + r) * K + c * 8;
        gB[1][j] = Bt + (size_t)e * sB + (size_t)(bn + 128 + r) * K + c * 8;
    }

    int aro[4], bro[4];
#pragma unroll
    for (int mt = 0; mt < 4; ++mt) {
        int r = wm * 64 + mt * 16 + m16;
        aro[mt] = r * 64 + (q ^ (r & 7)) * 8;
    }
#pragma unroll
    for (int nt = 0; nt < 4; ++nt) {
        int r = (wn & 1) * 64 + nt * 16 + m16;       // rows within the half
        bro[nt] = r * 64 + (q ^ (r & 7)) * 8;
    }

    auto STAGE_A = [&](int buf) {
#pragma unroll
        for (int j = 0; j < 2; ++j) { async_cp16(gA[j], &lds[buf][0][lofs[j]]); gA[j] += 64; }
    };
    auto STAGE_B = [&](int buf, int half) {
#pragma unroll
        for (int j = 0; j < 2; ++j) { async_cp16(gB[half][j], &lds[buf][1 + half][lofs[j]]); gB[half][j] += 64; }
    };

    const int nk = K >> 6;
    STAGE_A(0); STAGE_B(0, 0); STAGE_B(0, 1);
    if (nk > 1) {
        STAGE_B(1, 0); STAGE_B(1, 1);
        asm volatile("s_waitcnt vmcnt(4)" ::: "memory");   // tile0's 6 landed
    } else {
        asm volatile("s_waitcnt vmcnt(0)" ::: "memory");
    }
    BAR();

    f32x4 acc[4][4] = {};
    for (int ti = 0; ti < nk; ++ti) {
        const int cur = ti & 1, nx = cur ^ 1;
        const u16* lA = &lds[cur][0][0];
        const u16* lB = &lds[cur][1 + bh][0];
        bf16x8 a01[2][2], a23[2][2], b01[2][2], b23[2][2];

        // ---- phase 1: read a01 + b01 ; stage A(t+1)->nx ; Q(mt01,nt01)
#pragma unroll
        for (int mt = 0; mt < 2; ++mt)
#pragma unroll
            for (int kk = 0; kk < 2; ++kk)
                a01[mt][kk] = *(const bf16x8*)&lA[aro[mt] ^ (kk * 32)];
#pragma unroll
        for (int nt = 0; nt < 2; ++nt)
#pragma unroll
            for (int kk = 0; kk < 2; ++kk)
                b01[nt][kk] = *(const bf16x8*)&lB[bro[nt] ^ (kk * 32)];
        if (ti + 1 < nk) STAGE_A(nx);
        BAR();
        asm volatile("s_waitcnt lgkmcnt(0)" ::: "memory");
        __builtin_amdgcn_s_setprio(1);
#pragma unroll
        for (int mt = 0; mt < 2; ++mt)
#pragma unroll
            for (int nt = 0; nt < 2; ++nt)
#pragma unroll
                for (int kk = 0; kk < 2; ++kk)
                    acc[mt][nt] = __builtin_amdgcn_mfma_f32_16x16x32_bf16(
                        a01[mt][kk], b01[nt][kk], acc[mt][nt], 0, 0, 0);
        __builtin_amdgcn_s_setprio(0);
        BAR();

        // ---- phase 2: read b23 ; Q(mt01,nt23)
#pragma unroll
        for (int nt = 0; nt < 2; ++nt)
#pragma unroll
            for (int kk = 0; kk < 2; ++kk)
                b23[nt][kk] = *(const bf16x8*)&lB[bro[2 + nt] ^ (kk * 32)];
        BAR();
        asm volatile("s_waitcnt lgkmcnt(0)" ::: "memory");
        __builtin_amdgcn_s_setprio(1);
#pragma unroll
        for (int mt = 0; mt < 2; ++mt)
#pragma unroll
            for (int nt = 0; nt < 2; ++nt)
#pragma unroll
                for (int kk = 0; kk < 2; ++kk)
                    acc[mt][2 + nt] = __builtin_amdgcn_mfma_f32_16x16x32_bf16(
                        a01[mt][kk], b23[nt][kk], acc[mt][2 + nt], 0, 0, 0);
        __builtin_amdgcn_s_setprio(0);
        BAR();

        // ---- phase 3: read a23 ; stage B(t+2)h0->cur ; Q(mt23,nt23)
#pragma unroll
        for (int mt = 0; mt < 2; ++mt)
#pragma unroll
            for (int kk = 0; kk < 2; ++kk)
                a23[mt][kk] = *(const bf16x8*)&lA[aro[2 + mt] ^ (kk * 32)];
        if (ti + 2 < nk) STAGE_B(cur, 0);
        BAR();
        asm volatile("s_waitcnt lgkmcnt(0)" ::: "memory");
        __builtin_amdgcn_s_setprio(1);
#pragma unroll
        for (int mt = 0; mt < 2; ++mt)
#pragma unroll
            for (int nt = 0; nt < 2; ++nt)
#pragma unroll
                for (int kk = 0; kk < 2; ++kk)
                    acc[2 + mt][2 + nt] = __builtin_amdgcn_mfma_f32_16x16x32_bf16(
                        a23[mt][kk], b23[nt][kk], acc[2 + mt][2 + nt], 0, 0, 0);
        __builtin_amdgcn_s_setprio(0);
        BAR();

        // ---- phase 4: stage B(t+2)h1->cur ; Q(mt23,nt01) ; counted vmcnt
        if (ti + 2 < nk) STAGE_B(cur, 1);
        BAR();
        __builtin_amdgcn_s_setprio(1);
#pragma unroll
        for (int mt = 0; mt < 2; ++mt)
#pragma unroll
            for (int nt = 0; nt < 2; ++nt)
#pragma unroll
                for (int kk = 0; kk < 2; ++kk)
                    acc[2 + mt][nt] = __builtin_amdgcn_mfma_f32_16x16x32_bf16(
                        a23[mt][kk], b01[nt][kk], acc[2 + mt][nt], 0, 0, 0);
        __builtin_amdgcn_s_setprio(0);
        if (ti + 1 < nk) {
            if (ti + 2 < nk) asm volatile("s_waitcnt vmcnt(4)" ::: "memory");
            else             asm volatile("s_waitcnt vmcnt(0)" ::: "memory");
        }
        BAR();
    }

    const size_t cbase = (size_t)e * sC;
#pragma unroll
    for (int mt = 0; mt < 4; ++mt)
#pragma unroll
        for (int nt = 0; nt < 4; ++nt)
#pragma unroll
            for (int r2 = 0; r2 < 4; ++r2) {
                int row = bm + wm * 64 + mt * 16 + q * 4 + r2;
                int col = bn + wn * 64 + nt * 16 + m16;
                C[cbase + (size_t)row * N + col] = f2bf(acc[mt][nt][r2]);
            }
}

// --------------------------------------------------------------- combine ---
__global__ __launch_bounds__(256) void combine_kernel(const u16* __restrict__ eo,
                                                      const float* __restrict__ weights,
                                                      const float* __restrict__ maskf,
                                                      const int* __restrict__ pos_tok,
                                                      float* __restrict__ out)
{
    int token = blockIdx.x;
    int tid   = threadIdx.x;
    int b = token >> 11;
    int c = pos_tok[token];
    float a0 = 0.f, a1 = 0.f;
    if (c < CAPC) {
        const float* wr = weights + (size_t)token * EC;
        const float* mr = maskf   + (size_t)token * EC;
#pragma unroll
        for (int e = 0; e < EC; ++e) {
            float wm = wr[e] * mr[e];
            if (wm != 0.f) {
                const u16* src = eo + (((size_t)e * BC + b) * CAPC + c) * DIMC;
                unsigned u = *(const unsigned*)(src + 2 * tid);
                a0 += wm * bf2f(u & 0xffffu);
                a1 += wm * bf2f(u >> 16);
            }
        }
    }
    *(float2*)(out + (size_t)token * DIMC + 2 * tid) = make_float2(a0, a1);
}

__global__ void loss_kernel(const float* __restrict__ density,
                            const float* __restrict__ proxy,
                            float* __restrict__ out_loss)
{
    __shared__ float sh[BC * EC];
    int t = threadIdx.x;
    sh[t] = density[t] * proxy[t];
    __syncthreads();
    for (int s2 = (BC * EC) / 2; s2 >= 1; s2 >>= 1) {
        if (t < s2) sh[t] += sh[t + s2];
        __syncthreads();
    }
    if (t == 0)
        out_loss[0] = sh[0] * ((float)(EC * EC) / (float)(BC * EC)) * 0.01f;
}

// ---------------------------------------------------------------- launch ---
extern "C" void kernel_launch(void* const* d_in, const int* in_sizes, int n_in,
                              void* d_out, int out_size, void* d_ws, size_t ws_size,
                              hipStream_t stream)
{
    const float* x  = (const float*)d_in[0];
    const float* wg = (const float*)d_in[1];
    const float* w1 = (const float*)d_in[2];
    const float* w2 = (const float*)d_in[3];
    float* out = (float*)d_out;

    char* ws = (char*)d_ws;
    size_t off = 0;
    auto alloc = [&](size_t bytes) -> void* {
        void* p = ws + off;
        off = (off + bytes + 255) & ~(size_t)255;
        return p;
    };
    float* raw      = (float*)alloc((size_t)BN * EC * 4);
    float* weights  = (float*)alloc((size_t)BN * EC * 4);
    float* maskf    = (float*)alloc((size_t)BN * EC * 4);
    int*   pos      = (int*)  alloc((size_t)BN * EC * 4);
    int*   pos_tok  = (int*)  alloc((size_t)BN * 4);
    int*   heads    = (int*)  alloc((size_t)EC * BC * CAPC * 4);
    int*   nxt      = (int*)  alloc((size_t)EC * BC * CAPC * 4);
    int*   node_tok = (int*)  alloc((size_t)EC * BC * CAPC * 4);
    float* density  = (float*)alloc(BC * EC * 4);
    float* proxy    = (float*)alloc(BC * EC * 4);
    u16*   ei_bf    = (u16*)alloc((size_t)EC * BC * CAPC * DIMC * 2);
    u16*   w1t      = (u16*)alloc((size_t)EC * DIMC * HIDC * 2);
    u16*   w2t      = (u16*)alloc((size_t)EC * HIDC * DIMC * 2);
    u16*   eo_bf    = (u16*)alloc((size_t)EC * BC * CAPC * DIMC * 2);
    size_t hid_full = (size_t)EC * BC * CAPC * HIDC * 2;     // 128 MiB
    int ngroups = (ws_size - off >= hid_full) ? 1 : 2;
    int EG = EC / ngroups;
    u16* hidden = (u16*)alloc((size_t)EG * BC * CAPC * HIDC * 2);

    (void)in_sizes; (void)n_in; (void)out_size;

    init_kernel<<<(EC * BC * CAPC + 255) / 256, 256, 0, stream>>>(heads, pos_tok);
    transpose_cvt_all_kernel<<<8192, 256, 0, stream>>>(w1, w2, w1t, w2t);

    gate_kernel<<<BN / 16, 256, 0, stream>>>(x, wg, raw, weights, maskf);
    capacity_kernel<<<BC * EC, 64, 0, stream>>>(raw, maskf, pos, pos_tok, density, proxy);
    build_kernel<<<BN * EC / 256, 256, 0, stream>>>(maskf, pos, pos_tok, heads, nxt, node_tok);
    gather_ei_kernel<<<EC * BC * CAPC / 4, 256, 0, stream>>>(x, heads, nxt, node_tok, ei_bf);

    for (int g = 0; g < ngroups; ++g) {
        const u16* Ag  = ei_bf + (size_t)g * EG * BC * CAPC * DIMC;
        const u16* B1g = w1t   + (size_t)g * EG * DIMC * HIDC;
        gemm256_kernel<1><<<(HIDC / 256) * ((BC * CAPC) / 256) * EG, 512, 0, stream>>>(
            Ag, B1g, hidden, BC * CAPC, HIDC, DIMC,
            (long)BC * CAPC * DIMC, (long)HIDC * DIMC, (long)BC * CAPC * HIDC);
        const u16* B2g = w2t + (size_t)g * EG * HIDC * DIMC;
        u16* Eg = eo_bf + (size_t)g * EG * BC * CAPC * DIMC;
        gemm_ffn2_kernel<<<(DIMC / 256) * ((BC * CAPC) / 128) * EG, 512, 0, stream>>>(
            hidden, B2g, Eg, DIMC, HIDC,
            (long)BC * CAPC * HIDC, (long)DIMC * HIDC, (long)BC * CAPC * DIMC);
    }

    combine_kernel<<<BN, 256, 0, stream>>>(eo_bf, weights, maskf, pos_tok, out);
    loss_kernel<<<1, BC * EC, 0, stream>>>(density, proxy, out + (size_t)BN * DIMC);
}